// Round 5
// baseline (3269.400 us; speedup 1.0000x reference)
//
#include <hip/hip_runtime.h>
#include <math.h>

typedef float f2 __attribute__((ext_vector_type(2)));
typedef float f4 __attribute__((ext_vector_type(4)));

#define BN 8
#define CIN 3
#define HH 512
#define WW 512
#define KK 9
#define OFFC 27
#define PATCH 27

// ws layout (d_ws): for patch elem i in 0..26: 28 floats = 14 pairs:
//   pair q (q<13): (w_off[2q][i], w_off[2q+1][i]); pair 13: (w_off[26][i], 0)
// where w_off[ch][i] = w_off[ch*27 + i], i = c*9+t.
__global__ void reorder_weights(const float* __restrict__ w_off, float* __restrict__ ws)
{
    for (int idx = threadIdx.x; idx < PATCH * 28; idx += blockDim.x) {
        const int i = idx / 28;
        const int r = idx % 28;       // 2*q + half
        const int q = r >> 1;
        const int half = r & 1;
        float v;
        if (q < 13)      v = w_off[(2 * q + half) * PATCH + i];
        else if (!half)  v = w_off[26 * PATCH + i];
        else             v = 0.0f;
        ws[idx] = v;
    }
}

__global__ __launch_bounds__(256, 4) void deform_fused_kernel(
    const float* __restrict__ x,
    const float* __restrict__ wsw,    // reordered offset-conv weights, 756 floats
    const float* __restrict__ b_off,
    const float* __restrict__ w_def,
    const float* __restrict__ b_def,
    float* __restrict__ out)
{
    __shared__ __attribute__((aligned(16))) float s_w[PATCH * 28];  // 756 floats
    __shared__ f2 s_bop[14];          // b_off pairs
    __shared__ f2 s_wd01[PATCH];      // (w_def[0][i], w_def[1][i])
    __shared__ float s_wd2[PATCH];    // w_def[2][i]

    {
        const int tid = threadIdx.x;
        const f4* src4 = (const f4*)wsw;
        f4* dst4 = (f4*)s_w;
        for (int i = tid; i < PATCH * 7; i += blockDim.x) dst4[i] = src4[i];
        if (tid < 14) {
            f2 bp;
            bp.x = b_off[2 * tid < OFFC ? 2 * tid : 26];
            bp.y = (2 * tid + 1 < OFFC) ? b_off[2 * tid + 1] : 0.0f;
            s_bop[tid] = bp;
        }
        if (tid < PATCH) {
            f2 wd;
            wd.x = w_def[tid];
            wd.y = w_def[PATCH + tid];
            s_wd01[tid] = wd;
            s_wd2[tid] = w_def[2 * PATCH + tid];
        }
    }
    __syncthreads();

    const int w = blockIdx.x * blockDim.x + threadIdx.x;
    const int h = blockIdx.y;
    const int b = blockIdx.z;

    const size_t plane = (size_t)HH * WW;
    const float* xb = x + (size_t)b * CIN * plane;

    // ---- 3x3x3 zero-padded patch, flat index = c*9 + t ----
    float patch[PATCH];
    #pragma unroll
    for (int c = 0; c < CIN; ++c) {
        const float* xp = xb + c * plane;
        #pragma unroll
        for (int t = 0; t < KK; ++t) {
            const int yy = h + t / 3 - 1;
            const int xx = w + t % 3 - 1;
            const bool in = (yy >= 0) & (yy < HH) & (xx >= 0) & (xx < WW);
            patch[c * KK + t] = in ? xp[yy * WW + xx] : 0.0f;
        }
    }

    // ---- offset conv: 27 channels as 14 packed pairs (pair13.y is dummy) ----
    f2 ow[14];
    #pragma unroll
    for (int q = 0; q < 14; ++q) ow[q] = s_bop[q];

    const f4* sw4 = (const f4*)s_w;
    #pragma unroll
    for (int i = 0; i < PATCH; ++i) {
        const float p = patch[i];
        const f2 pp = { p, p };
        #pragma unroll
        for (int j = 0; j < 7; ++j) {
            const f4 wq = sw4[i * 7 + j];
            const f2 lo = { wq.x, wq.y };
            const f2 hi = { wq.z, wq.w };
            ow[2 * j]     = __builtin_elementwise_fma(lo, pp, ow[2 * j]);
            ow[2 * j + 1] = __builtin_elementwise_fma(hi, pp, ow[2 * j + 1]);
        }
    }

    // ---- deformable sampling + output contraction ----
    f2 acc01 = { b_def[0], b_def[1] };
    float acc2 = b_def[2];

    #pragma unroll
    for (int k = 0; k < KK; ++k) {
        const float oy = ow[k].x;
        const float ox = ow[k].y;
        const float om = (k < 8) ? ((k & 1) ? ow[9 + (k >> 1)].y
                                            : ow[9 + (k >> 1)].x)
                                 : ow[13].x;

        const float m = 1.0f / (1.0f + __expf(-om));

        const float py = (float)h + (float)(k / 3 - 1) + oy;
        const float px = (float)w + (float)(k % 3 - 1) + ox;
        const float y0f = floorf(py);
        const float x0f = floorf(px);
        const float dy = py - y0f;
        const float dx = px - x0f;
        const int y0 = (int)y0f;
        const int x0 = (int)x0f;

        const f2 dxp = { 1.0f - dx, dx };
        const f2 dyT = { 1.0f - dy, 1.0f - dy };
        const f2 dyB = { dy, dy };
        const f2 wT = dxp * dyT;   // (w00, w01)
        const f2 wB = dxp * dyB;   // (w10, w11)

        const int interior = (y0 >= 0) & (y0 + 1 < HH) & (x0 >= 0) & (x0 + 1 < WW);

        if (__all(interior)) {
            const int idx = y0 * WW + x0;
            #pragma unroll
            for (int c = 0; c < CIN; ++c) {
                const float* xp = xb + c * plane + idx;
                const f2 vT = { xp[0], xp[1] };
                const f2 vB = { xp[WW], xp[WW + 1] };
                f2 s = vT * wT;
                s = __builtin_elementwise_fma(vB, wB, s);
                const float val = (s.x + s.y) * m;
                const f2 vv = { val, val };
                acc01 = __builtin_elementwise_fma(s_wd01[c * KK + k], vv, acc01);
                acc2 = fmaf(s_wd2[c * KK + k], val, acc2);
            }
        } else {
            const bool vy0 = (y0 >= 0)     & (y0 < HH);
            const bool vy1 = (y0 + 1 >= 0) & (y0 + 1 < HH);
            const bool vx0 = (x0 >= 0)     & (x0 < WW);
            const bool vx1 = (x0 + 1 >= 0) & (x0 + 1 < WW);

            const int yc0 = min(max(y0, 0), HH - 1);
            const int yc1 = min(max(y0 + 1, 0), HH - 1);
            const int xc0 = min(max(x0, 0), WW - 1);
            const int xc1 = min(max(x0 + 1, 0), WW - 1);

            #pragma unroll
            for (int c = 0; c < CIN; ++c) {
                const float* xp = xb + c * plane;
                const float v00 = (vy0 & vx0) ? xp[yc0 * WW + xc0] : 0.0f;
                const float v01 = (vy0 & vx1) ? xp[yc0 * WW + xc1] : 0.0f;
                const float v10 = (vy1 & vx0) ? xp[yc1 * WW + xc0] : 0.0f;
                const float v11 = (vy1 & vx1) ? xp[yc1 * WW + xc1] : 0.0f;

                const float val =
                    (v00 * wT.x + v01 * wT.y + v10 * wB.x + v11 * wB.y) * m;
                const f2 vv = { val, val };
                acc01 = __builtin_elementwise_fma(s_wd01[c * KK + k], vv, acc01);
                acc2 = fmaf(s_wd2[c * KK + k], val, acc2);
            }
        }
    }

    const size_t base = (size_t)b * (CIN * plane) + (size_t)h * WW + w;
    out[base]             = acc01.x;
    out[base + plane]     = acc01.y;
    out[base + 2 * plane] = acc2;
}

extern "C" void kernel_launch(void* const* d_in, const int* in_sizes, int n_in,
                              void* d_out, int out_size, void* d_ws, size_t ws_size,
                              hipStream_t stream) {
    const float* x     = (const float*)d_in[0];
    const float* w_off = (const float*)d_in[1];
    const float* b_off = (const float*)d_in[2];
    const float* w_def = (const float*)d_in[3];
    const float* b_def = (const float*)d_in[4];
    float* out = (float*)d_out;
    float* wsw = (float*)d_ws;   // 756 floats of reordered weights

    reorder_weights<<<1, 256, 0, stream>>>(w_off, wsw);

    dim3 block(256, 1, 1);
    dim3 grid(WW / 256, HH, BN);  // (2, 512, 8)
    deform_fused_kernel<<<grid, block, 0, stream>>>(x, wsw, b_off, w_def, b_def, out);
}

// Round 6
// 187.812 us; speedup vs baseline: 17.4079x; 17.4079x over previous
//
#include <hip/hip_runtime.h>
#include <math.h>

typedef float f2 __attribute__((ext_vector_type(2)));
typedef float f2u __attribute__((ext_vector_type(2), aligned(4)));
typedef float f4 __attribute__((ext_vector_type(4)));

#define BN 8
#define CIN 3
#define HH 512
#define WW 512
#define KK 9
#define OFFC 27
#define PATCH 27
#define TAPBLK 84  // per-tap: 28 (wy,wx) pairs (56 floats, pair 27 = 0) + wm[28] (pad 0)

// ws layout: tap k block of 84 floats:
//   r in [0,56): pair q=r>>1 (patch elem), half=r&1 -> w_off[(2k+half)*27 + q], q>=27 -> 0
//   r in [56,84): i=r-56 -> w_off[(18+k)*27 + i], i>=27 -> 0
__global__ void reorder_weights(const float* __restrict__ w_off, float* __restrict__ ws)
{
    for (int idx = threadIdx.x; idx < KK * TAPBLK; idx += blockDim.x) {
        const int k = idx / TAPBLK;
        const int r = idx % TAPBLK;
        float v = 0.0f;
        if (r < 56) {
            const int q = r >> 1, half = r & 1;
            if (q < PATCH) v = w_off[(2 * k + half) * PATCH + q];
        } else {
            const int i = r - 56;
            if (i < PATCH) v = w_off[(18 + k) * PATCH + i];
        }
        ws[idx] = v;
    }
}

__global__ __launch_bounds__(256) void deform_fused_kernel(
    const float* __restrict__ x,
    const float* __restrict__ wsw,    // reordered offset-conv weights, 756 floats
    const float* __restrict__ b_off,
    const float* __restrict__ w_def,
    const float* __restrict__ b_def,
    float* __restrict__ out)
{
    __shared__ __attribute__((aligned(16))) float s_w[KK * TAPBLK];  // 756 floats
    __shared__ f2 s_boyx[KK];        // (b_off[2k], b_off[2k+1])
    __shared__ float s_bom[KK];      // b_off[18+k]
    __shared__ f2 s_wd01[PATCH];     // (w_def[0][i], w_def[1][i])
    __shared__ float s_wd2[PATCH];   // w_def[2][i]
    __shared__ float s_bdef[3];

    {
        const int tid = threadIdx.x;
        const f4* src4 = (const f4*)wsw;
        f4* dst4 = (f4*)s_w;
        for (int i = tid; i < KK * TAPBLK / 4; i += blockDim.x) dst4[i] = src4[i];
        if (tid < KK) {
            f2 bp = { b_off[2 * tid], b_off[2 * tid + 1] };
            s_boyx[tid] = bp;
            s_bom[tid] = b_off[18 + tid];
        }
        if (tid < PATCH) {
            f2 wd = { w_def[tid], w_def[PATCH + tid] };
            s_wd01[tid] = wd;
            s_wd2[tid] = w_def[2 * PATCH + tid];
        }
        if (tid < 3) s_bdef[tid] = b_def[tid];
    }
    __syncthreads();

    const int w = blockIdx.x * blockDim.x + threadIdx.x;
    const int h = blockIdx.y;
    const int b = blockIdx.z;

    const size_t plane = (size_t)HH * WW;
    const float* xb = x + (size_t)b * CIN * plane;

    // ---- 3x3x3 zero-padded patch, flat index = c*9 + t; pad elem 27 = 0 ----
    float patch[28];
    patch[27] = 0.0f;
    #pragma unroll
    for (int c = 0; c < CIN; ++c) {
        const float* xp = xb + c * plane;
        #pragma unroll
        for (int t = 0; t < KK; ++t) {
            const int yy = h + t / 3 - 1;
            const int xx = w + t % 3 - 1;
            const bool in = (yy >= 0) & (yy < HH) & (xx >= 0) & (xx < WW);
            patch[c * KK + t] = in ? xp[yy * WW + xx] : 0.0f;
        }
    }

    f2 acc01 = { s_bdef[0], s_bdef[1] };
    float acc2 = s_bdef[2];

    #pragma unroll 1
    for (int k = 0; k < KK; ++k) {
        // ---- per-tap conv: (oy,ox) packed, om scalar ----
        f2 oyx = s_boyx[k];
        float om = s_bom[k];

        const f4* pw = (const f4*)&s_w[k * TAPBLK];        // 14 f4 = 28 (wy,wx) pairs
        #pragma unroll
        for (int j = 0; j < 14; ++j) {
            const f4 wq = pw[j];
            const float p0 = patch[2 * j];
            const float p1 = patch[2 * j + 1];
            const f2 w0 = { wq.x, wq.y };
            const f2 w1 = { wq.z, wq.w };
            const f2 pp0 = { p0, p0 };
            const f2 pp1 = { p1, p1 };
            oyx = __builtin_elementwise_fma(w0, pp0, oyx);
            oyx = __builtin_elementwise_fma(w1, pp1, oyx);
        }
        const f4* pm = (const f4*)&s_w[k * TAPBLK + 56];   // 7 f4 = wm[28]
        #pragma unroll
        for (int j = 0; j < 7; ++j) {
            const f4 wm4 = pm[j];
            om = fmaf(wm4.x, patch[4 * j],     om);
            om = fmaf(wm4.y, patch[4 * j + 1], om);
            om = fmaf(wm4.z, patch[4 * j + 2], om);
            om = fmaf(wm4.w, patch[4 * j + 3], om);
        }

        const float m = 1.0f / (1.0f + __expf(-om));

        const float py = (float)h + (float)(k / 3 - 1) + oyx.x;
        const float px = (float)w + (float)(k % 3 - 1) + oyx.y;
        const float y0f = floorf(py);
        const float x0f = floorf(px);
        const float dy = py - y0f;
        const float dx = px - x0f;
        const int y0 = (int)y0f;
        const int x0 = (int)x0f;

        const f2 dxp = { 1.0f - dx, dx };
        const f2 wT = dxp * (1.0f - dy);   // (w00, w01)
        const f2 wB = dxp * dy;            // (w10, w11)

        const int interior = (y0 >= 0) & (y0 + 1 < HH) & (x0 >= 0) & (x0 + 1 < WW);

        if (__all(interior)) {
            const int idx = y0 * WW + x0;
            #pragma unroll
            for (int c = 0; c < CIN; ++c) {
                const float* xp = xb + c * plane + idx;
                const f2 vT = *(const f2u*)(xp);
                const f2 vB = *(const f2u*)(xp + WW);
                f2 s = vT * wT;
                s = __builtin_elementwise_fma(vB, wB, s);
                const float val = (s.x + s.y) * m;
                const f2 vv = { val, val };
                acc01 = __builtin_elementwise_fma(s_wd01[c * KK + k], vv, acc01);
                acc2 = fmaf(s_wd2[c * KK + k], val, acc2);
            }
        } else {
            const bool vy0 = (y0 >= 0)     & (y0 < HH);
            const bool vy1 = (y0 + 1 >= 0) & (y0 + 1 < HH);
            const bool vx0 = (x0 >= 0)     & (x0 < WW);
            const bool vx1 = (x0 + 1 >= 0) & (x0 + 1 < WW);

            const int yc0 = min(max(y0, 0), HH - 1);
            const int yc1 = min(max(y0 + 1, 0), HH - 1);
            const int xc0 = min(max(x0, 0), WW - 1);
            const int xc1 = min(max(x0 + 1, 0), WW - 1);

            #pragma unroll
            for (int c = 0; c < CIN; ++c) {
                const float* xp = xb + c * plane;
                const float v00 = (vy0 & vx0) ? xp[yc0 * WW + xc0] : 0.0f;
                const float v01 = (vy0 & vx1) ? xp[yc0 * WW + xc1] : 0.0f;
                const float v10 = (vy1 & vx0) ? xp[yc1 * WW + xc0] : 0.0f;
                const float v11 = (vy1 & vx1) ? xp[yc1 * WW + xc1] : 0.0f;

                const float val =
                    (v00 * wT.x + v01 * wT.y + v10 * wB.x + v11 * wB.y) * m;
                const f2 vv = { val, val };
                acc01 = __builtin_elementwise_fma(s_wd01[c * KK + k], vv, acc01);
                acc2 = fmaf(s_wd2[c * KK + k], val, acc2);
            }
        }
    }

    const size_t base = (size_t)b * (CIN * plane) + (size_t)h * WW + w;
    out[base]             = acc01.x;
    out[base + plane]     = acc01.y;
    out[base + 2 * plane] = acc2;
}

extern "C" void kernel_launch(void* const* d_in, const int* in_sizes, int n_in,
                              void* d_out, int out_size, void* d_ws, size_t ws_size,
                              hipStream_t stream) {
    const float* x     = (const float*)d_in[0];
    const float* w_off = (const float*)d_in[1];
    const float* b_off = (const float*)d_in[2];
    const float* w_def = (const float*)d_in[3];
    const float* b_def = (const float*)d_in[4];
    float* out = (float*)d_out;
    float* wsw = (float*)d_ws;   // 756 floats of reordered weights

    reorder_weights<<<1, 256, 0, stream>>>(w_off, wsw);

    dim3 block(256, 1, 1);
    dim3 grid(WW / 256, HH, BN);  // (2, 512, 8)
    deform_fused_kernel<<<grid, block, 0, stream>>>(x, wsw, b_off, w_def, b_def, out);
}